// Round 1
// baseline (1137.169 us; speedup 1.0000x reference)
//
#include <hip/hip_runtime.h>
#include <hip/hip_bf16.h>

// VectorQuantizer forward, MI355X fp32 implementation.
// T=4096 tokens, NE=16384 codes, K=256 (split 64 + 192).
// Outputs (flat float32): z_q NCHW [1048576], vq, commit, entropy, vqkd_d_norm,
// vqgan_d_norm, idx-as-float [4096]. Total 1052677.

#define T_TOK   4096
#define NE      16384
#define KDIM    256
#define K0S     64          // split0
#define CAP     512         // candidate cap per token

#define BM 128
#define BN 128
#define BK 32
#define TM 8
#define TN 8

// ---------------- init ----------------
__global__ void vq_init_kernel(unsigned long long* __restrict__ packed,
                               float* __restrict__ avg_num,
                               int* __restrict__ ncand,
                               float* __restrict__ scal) {
    int i = blockIdx.x * 256 + threadIdx.x;
    if (i < T_TOK) packed[i] = ~0ull;
    if (i < NE)    avg_num[i] = 0.f;
    if (i < T_TOK) ncand[i] = 0;
    if (i < 8)     scal[i] = 0.f;
}

// ---------------- normalize codebooks ----------------
__global__ void norm_codes_kernel(const float* __restrict__ wk, const float* __restrict__ wg,
                                  float* __restrict__ enorm,
                                  float* __restrict__ e2k, float* __restrict__ e2g) {
    int n = blockIdx.x;
    int c = threadIdx.x;
    __shared__ float red[256];
    __shared__ float s_nk, s_ng;
    float x = (c < K0S) ? wk[n * K0S + c] : wg[n * (KDIM - K0S) + (c - K0S)];
    red[c] = x * x;
    __syncthreads();
    if (c == 0) { float s = 0.f; for (int i = 0; i < K0S; ++i) s += red[i];
                  s_nk = fmaxf(sqrtf(s), 1e-12f); }
    if (c == 1) { float s = 0.f; for (int i = K0S; i < KDIM; ++i) s += red[i];
                  s_ng = fmaxf(sqrtf(s), 1e-12f); }
    __syncthreads();
    float y = x / ((c < K0S) ? s_nk : s_ng);
    enorm[n * KDIM + c] = y;
    red[c] = y * y;
    __syncthreads();
    if (c == 0) { float s = 0.f; for (int i = 0; i < K0S; ++i) s += red[i]; e2k[n] = s; }
    if (c == 1) { float s = 0.f; for (int i = K0S; i < KDIM; ++i) s += red[i]; e2g[n] = s; }
}

// ---------------- normalize z (with NCHW -> token transpose) ----------------
__global__ void norm_z_kernel(const float* __restrict__ z,
                              float* __restrict__ znorm,
                              float* __restrict__ z2k, float* __restrict__ z2g) {
    int t = blockIdx.x;
    int c = threadIdx.x;
    int b = t >> 10, hw = t & 1023;
    __shared__ float red[256];
    __shared__ float s_nk, s_ng;
    float x = z[((size_t)b * 256 + c) * 1024 + hw];
    red[c] = x * x;
    __syncthreads();
    if (c == 0) { float s = 0.f; for (int i = 0; i < K0S; ++i) s += red[i];
                  s_nk = fmaxf(sqrtf(s), 1e-12f); }
    if (c == 1) { float s = 0.f; for (int i = K0S; i < KDIM; ++i) s += red[i];
                  s_ng = fmaxf(sqrtf(s), 1e-12f); }
    __syncthreads();
    float y = x / ((c < K0S) ? s_nk : s_ng);
    znorm[t * KDIM + c] = y;
    red[c] = y * y;
    __syncthreads();
    if (c == 0) { float s = 0.f; for (int i = 0; i < K0S; ++i) s += red[i]; z2k[t] = s; }
    if (c == 1) { float s = 0.f; for (int i = K0S; i < KDIM; ++i) s += red[i]; z2g[t] = s; }
}

// ---------------- main GEMM: MODE 0 = argmin + d^2 sums, MODE 1 = candidate capture ----------------
template <int MODE>
__global__ __launch_bounds__(256, 2)
void gemm_kernel(const float* __restrict__ znorm, const float* __restrict__ enorm,
                 const float* __restrict__ z2k, const float* __restrict__ z2g,
                 const float* __restrict__ e2k, const float* __restrict__ e2g,
                 unsigned long long* __restrict__ packed, float* __restrict__ scal,
                 const float* __restrict__ m_arr,
                 float* __restrict__ candD, int* __restrict__ candN, int* __restrict__ ncand) {
    __shared__ float As[BK][BM];
    __shared__ float Bs[BK][BN];

    const int tid = threadIdx.x;
    const int tx = tid & 15;
    const int ty = tid >> 4;
    const int n0 = blockIdx.x * BN;
    const int t0 = blockIdx.y * BM;
    const int lt = tid & 127;
    const int qb = tid >> 7;   // 0 or 1

    float acck[TM][TN], accg[TM][TN];
#pragma unroll
    for (int i = 0; i < TM; ++i)
#pragma unroll
        for (int j = 0; j < TN; ++j) { acck[i][j] = 0.f; accg[i][j] = 0.f; }

    auto chunk = [&](int k0, float (&acc)[TM][TN]) {
#pragma unroll
        for (int q = qb; q < 8; q += 2) {
            float4 va = *reinterpret_cast<const float4*>(&znorm[(size_t)(t0 + lt) * KDIM + k0 + q * 4]);
            float4 vb = *reinterpret_cast<const float4*>(&enorm[(size_t)(n0 + lt) * KDIM + k0 + q * 4]);
            As[q * 4 + 0][lt] = va.x; As[q * 4 + 1][lt] = va.y;
            As[q * 4 + 2][lt] = va.z; As[q * 4 + 3][lt] = va.w;
            Bs[q * 4 + 0][lt] = vb.x; Bs[q * 4 + 1][lt] = vb.y;
            Bs[q * 4 + 2][lt] = vb.z; Bs[q * 4 + 3][lt] = vb.w;
        }
        __syncthreads();
#pragma unroll 4
        for (int k = 0; k < BK; ++k) {
            float4 a0 = *reinterpret_cast<const float4*>(&As[k][ty * 4]);
            float4 a1 = *reinterpret_cast<const float4*>(&As[k][64 + ty * 4]);
            float4 b0 = *reinterpret_cast<const float4*>(&Bs[k][tx * 4]);
            float4 b1 = *reinterpret_cast<const float4*>(&Bs[k][64 + tx * 4]);
            float av[8] = {a0.x, a0.y, a0.z, a0.w, a1.x, a1.y, a1.z, a1.w};
            float bv[8] = {b0.x, b0.y, b0.z, b0.w, b1.x, b1.y, b1.z, b1.w};
#pragma unroll
            for (int i = 0; i < TM; ++i)
#pragma unroll
                for (int j = 0; j < TN; ++j)
                    acc[i][j] = fmaf(av[i], bv[j], acc[i][j]);
        }
        __syncthreads();
    };

    for (int kc = 0; kc < 2; ++kc) chunk(kc * BK, acck);   // k < 64  -> dot_k
    for (int kc = 2; kc < 8; ++kc) chunk(kc * BK, accg);   // k >= 64 -> dot_g

    // ---- epilogue ----
    int tIdx[TM], nIdx[TN];
#pragma unroll
    for (int i = 0; i < TM; ++i) tIdx[i] = t0 + ((i < 4) ? ty * 4 + i : 64 + ty * 4 + (i - 4));
#pragma unroll
    for (int j = 0; j < TN; ++j) nIdx[j] = n0 + ((j < 4) ? tx * 4 + j : 64 + tx * 4 + (j - 4));

    float z2kv[TM], z2gv[TM], mv[TM];
#pragma unroll
    for (int i = 0; i < TM; ++i) {
        z2kv[i] = z2k[tIdx[i]];
        z2gv[i] = z2g[tIdx[i]];
        if (MODE == 1) mv[i] = m_arr[tIdx[i]];
    }
    float e2kv[TN], e2gv[TN];
#pragma unroll
    for (int j = 0; j < TN; ++j) { e2kv[j] = e2k[nIdx[j]]; e2gv[j] = e2g[nIdx[j]]; }

    if (MODE == 0) {
        float sdk2 = 0.f, sdg2 = 0.f;
        unsigned long long pmin[TM];
#pragma unroll
        for (int i = 0; i < TM; ++i) pmin[i] = ~0ull;
#pragma unroll
        for (int i = 0; i < TM; ++i) {
#pragma unroll
            for (int j = 0; j < TN; ++j) {
                float dk = z2kv[i] + e2kv[j] - 2.f * acck[i][j];
                float dg = z2gv[i] + e2gv[j] - 2.f * accg[i][j];
                float d = dk + dg;
                sdk2 = fmaf(dk, dk, sdk2);
                sdg2 = fmaf(dg, dg, sdg2);
                unsigned long long pv =
                    (((unsigned long long)__float_as_uint(d)) << 32) | (unsigned)nIdx[j];
                if (pv < pmin[i]) pmin[i] = pv;
            }
        }
        // reduce min over tx lanes (lanes differing in bits 0..3 of lane id)
#pragma unroll
        for (int mmask = 1; mmask < 16; mmask <<= 1) {
#pragma unroll
            for (int i = 0; i < TM; ++i) {
                unsigned long long o = __shfl_xor(pmin[i], mmask, 64);
                if (o < pmin[i]) pmin[i] = o;
            }
        }
        if (tx == 0) {
#pragma unroll
            for (int i = 0; i < TM; ++i) atomicMin(&packed[tIdx[i]], pmin[i]);
        }
        // block-reduce the d^2 partial sums
        float* red = &As[0][0];
        red[tid] = sdk2;
        __syncthreads();
        for (int s = 128; s > 0; s >>= 1) { if (tid < s) red[tid] += red[tid + s]; __syncthreads(); }
        if (tid == 0) atomicAdd(&scal[0], red[0]);
        __syncthreads();
        red[tid] = sdg2;
        __syncthreads();
        for (int s = 128; s > 0; s >>= 1) { if (tid < s) red[tid] += red[tid + s]; __syncthreads(); }
        if (tid == 0) atomicAdd(&scal[1], red[0]);
    } else {
        // candidate capture: a - m >= -30  <=>  d <= dmin + 0.3
#pragma unroll
        for (int i = 0; i < TM; ++i) {
#pragma unroll
            for (int j = 0; j < TN; ++j) {
                float dk = z2kv[i] + e2kv[j] - 2.f * acck[i][j];
                float dg = z2gv[i] + e2gv[j] - 2.f * accg[i][j];
                float d = dk + dg;
                float a = -100.f * d;
                if (a - mv[i] >= -30.f) {
                    int t = tIdx[i];
                    int pos = atomicAdd(&ncand[t], 1);
                    if (pos < CAP) {
                        candD[t * CAP + pos] = d;
                        candN[t * CAP + pos] = nIdx[j];
                    }
                }
            }
        }
    }
}

// ---------------- unpack argmin ----------------
__global__ void argmin_kernel(const unsigned long long* __restrict__ packed,
                              float* __restrict__ m_arr, int* __restrict__ idx_arr,
                              float* __restrict__ out) {
    int t = blockIdx.x * 256 + threadIdx.x;
    if (t >= T_TOK) return;
    unsigned long long pv = packed[t];
    int idx = (int)(pv & 0xFFFFFFFFull);
    float dmin = __uint_as_float((unsigned)(pv >> 32));
    m_arr[t] = -100.f * dmin;
    idx_arr[t] = idx;
    out[1048581 + t] = (float)idx;
}

// ---------------- z_q gather + vq loss ----------------
__global__ void zq_kernel(const float* __restrict__ enorm, const float* __restrict__ znorm,
                          const int* __restrict__ idx_arr,
                          float* __restrict__ out, float* __restrict__ scal) {
    int t = blockIdx.x;
    int c = threadIdx.x;
    int b = t >> 10, hw = t & 1023;
    float q = enorm[(size_t)idx_arr[t] * KDIM + c];
    float zc = znorm[t * KDIM + c];
    out[((size_t)b * 256 + c) * 1024 + hw] = q;   // straight-through fwd == z_q, NCHW
    float df = q - zc;
    __shared__ float red[256];
    red[c] = df * df;
    __syncthreads();
    for (int s = 128; s > 0; s >>= 1) { if (c < s) red[c] += red[c + s]; __syncthreads(); }
    if (c == 0) atomicAdd(&scal[2], red[0]);
}

// ---------------- per-token softmax/entropy from candidates ----------------
__global__ void token_entropy_kernel(const float* __restrict__ candD, const int* __restrict__ candN,
                                     const int* __restrict__ ncand, const float* __restrict__ m_arr,
                                     float* __restrict__ avg_num, float* __restrict__ scal) {
    int t = blockIdx.x;
    int lane = threadIdx.x;  // 64
    int nc = min(ncand[t], CAP);
    float m = m_arr[t];
    float Z = 0.f, W = 0.f;
    for (int i = lane; i < nc; i += 64) {
        float a = -100.f * candD[t * CAP + i];
        float e = expf(a - m);
        Z += e;
        W = fmaf(e, a, W);
    }
#pragma unroll
    for (int mm = 1; mm < 64; mm <<= 1) {
        Z += __shfl_xor(Z, mm, 64);
        W += __shfl_xor(W, mm, 64);
    }
    if (lane == 0) {
        // -sum p log p = m + ln Z - (W/Z)   (sum over this token)
        atomicAdd(&scal[3], m + logf(Z) - W / Z);
    }
    for (int i = lane; i < nc; i += 64) {
        float a = -100.f * candD[t * CAP + i];
        float e = expf(a - m);
        atomicAdd(&avg_num[candN[t * CAP + i]], e / Z);
    }
}

// ---------------- final scalars ----------------
__global__ void finalize_kernel(const float* __restrict__ avg_num, const float* __restrict__ scal,
                                float* __restrict__ out) {
    __shared__ float red[256];
    int tid = threadIdx.x;
    float s = 0.f;
    for (int n = tid; n < NE; n += 256) {
        float avg = avg_num[n] * (1.f / 4096.f);
        s += avg * logf(avg + 1e-5f);
    }
    red[tid] = s;
    __syncthreads();
    for (int st = 128; st > 0; st >>= 1) { if (tid < st) red[tid] += red[tid + st]; __syncthreads(); }
    if (tid == 0) {
        float avg_ent = -red[0];
        float se = scal[3] * (1.f / 4096.f);
        float vq = scal[2] * (1.f / 1048576.f);
        out[1048576] = vq;
        out[1048577] = 0.25f * vq;                 // BETA * same forward value
        out[1048578] = 0.1f * (se - avg_ent);      // ENT_RATIO
        out[1048579] = scal[0] * (1.f / 4096.f);   // vqkd_d_norm
        out[1048580] = scal[1] * (1.f / 4096.f);   // vqgan_d_norm
    }
}

// ---------------- host ----------------
extern "C" void kernel_launch(void* const* d_in, const int* in_sizes, int n_in,
                              void* d_out, int out_size, void* d_ws, size_t ws_size,
                              hipStream_t stream) {
    const float* z  = (const float*)d_in[0];
    const float* wk = (const float*)d_in[1];
    const float* wg = (const float*)d_in[2];
    float* out = (float*)d_out;

    char* ws = (char*)d_ws;
    size_t off = 0;
    auto alloc = [&](size_t bytes) {
        void* p = ws + off;
        off += (bytes + 255) & ~(size_t)255;
        return p;
    };
    float* enorm  = (float*)alloc((size_t)NE * KDIM * 4);      // 16.78 MB
    float* znorm  = (float*)alloc((size_t)T_TOK * KDIM * 4);   // 4.19 MB
    float* e2k    = (float*)alloc(NE * 4);
    float* e2g    = (float*)alloc(NE * 4);
    float* z2k    = (float*)alloc(T_TOK * 4);
    float* z2g    = (float*)alloc(T_TOK * 4);
    unsigned long long* packed = (unsigned long long*)alloc(T_TOK * 8);
    float* m_arr  = (float*)alloc(T_TOK * 4);
    int*   idx_arr= (int*)alloc(T_TOK * 4);
    int*   ncand  = (int*)alloc(T_TOK * 4);
    float* candD  = (float*)alloc((size_t)T_TOK * CAP * 4);    // 8.39 MB
    int*   candN  = (int*)alloc((size_t)T_TOK * CAP * 4);      // 8.39 MB
    float* avg_num= (float*)alloc(NE * 4);
    float* scal   = (float*)alloc(8 * 4);
    // total ~38 MB of workspace

    vq_init_kernel<<<64, 256, 0, stream>>>(packed, avg_num, ncand, scal);
    norm_codes_kernel<<<NE, 256, 0, stream>>>(wk, wg, enorm, e2k, e2g);
    norm_z_kernel<<<T_TOK, 256, 0, stream>>>(z, znorm, z2k, z2g);

    dim3 gg(NE / BN, T_TOK / BM);
    gemm_kernel<0><<<gg, 256, 0, stream>>>(znorm, enorm, z2k, z2g, e2k, e2g,
                                           packed, scal, nullptr, nullptr, nullptr, nullptr);
    argmin_kernel<<<16, 256, 0, stream>>>(packed, m_arr, idx_arr, out);
    zq_kernel<<<T_TOK, 256, 0, stream>>>(enorm, znorm, idx_arr, out, scal);
    gemm_kernel<1><<<gg, 256, 0, stream>>>(znorm, enorm, z2k, z2g, e2k, e2g,
                                           packed, scal, m_arr, candD, candN, ncand);
    token_entropy_kernel<<<T_TOK, 64, 0, stream>>>(candD, candN, ncand, m_arr, avg_num, scal);
    finalize_kernel<<<1, 256, 0, stream>>>(avg_num, scal, out);
}